// Round 8
// baseline (5505.201 us; speedup 1.0000x reference)
//
#include <hip/hip_runtime.h>

typedef unsigned short ushort_t;
typedef __attribute__((ext_vector_type(8))) short v8s;
typedef __attribute__((ext_vector_type(4))) float v4f;
typedef __attribute__((ext_vector_type(4))) unsigned int v4u;
typedef __attribute__((ext_vector_type(4))) unsigned short v4h;

#define DEV __device__ __forceinline__

#define BB 128
#define TT 256
#define DD 256
#define UU 256
#define NG 1024
#define TB 32768  // T*B

#define L2E  1.4426950408889634f
#define L2E2 2.8853901617779268f

DEV ushort_t f2bf(float f){
  unsigned u = __builtin_bit_cast(unsigned, f);
  u = u + 0x7FFFu + ((u>>16)&1u);
  return (ushort_t)(u>>16);
}
DEV float bf2f(ushort_t h){
  unsigned u = ((unsigned)h)<<16;
  return __builtin_bit_cast(float, u);
}

// ---- prep: x (B,T,D) fp32 -> xb (T,B,D) bf16 ----
__global__ void prep_x(const float* __restrict__ x, ushort_t* __restrict__ xb){
  int tid = blockIdx.x*256 + threadIdx.x;
  int idx = tid*4;
  if (idx >= BB*TT*DD) return;
  int d0 = idx & 255, t = (idx>>8)&255, b = idx>>16;
  const float* s = x + ((size_t)(b*256+t))*256 + d0;
  ushort_t* o = xb + ((size_t)(t*128+b))*256 + d0;
  v4f v = *(const v4f*)s;
  o[0]=f2bf(v[0]); o[1]=f2bf(v[1]); o[2]=f2bf(v[2]); o[3]=f2bf(v[3]);
}

// ---- prep: W (L,K=256,N=1024) fp32 -> wt [d][L][n][k] bf16, pre-scaled by log2e ----
// gate = n>>8 (i,f,g,o); g-gate gets 2*log2e so gates become exp2-native.
__global__ void prep_w(const float* __restrict__ wf, const float* __restrict__ wb,
                       ushort_t* __restrict__ wt){
  int tid = blockIdx.x*256 + threadIdx.x;           // 1,048,576 total
  int n = tid & 1023, k = (tid>>10)&255, L = (tid>>18)&1, d = (tid>>19)&1;
  const float* src = (d ? wb : wf) + (size_t)L*262144 + (size_t)k*1024 + n;
  float sc = ((n>>8)==2) ? L2E2 : L2E;
  wt[(size_t)((d*2+L)*1024 + n)*256 + k] = f2bf(*src * sc);
}

// ---- prep: R (L,256,1024) fp32 -> rp packed in MFMA B-fragment order, pre-scaled ----
// slot = column/16 within direction (0..15). frag (ks,g), lane l, elem j holds
// R[ks*32+(l>>4)*8+j][g*256+slot*16+(l&15)] * sc
__global__ void prep_r(const float* __restrict__ rf, const float* __restrict__ rb,
                       ushort_t* __restrict__ rp){
  int tid = blockIdx.x*256 + threadIdx.x;           // 1,048,576 total
  int gcol = tid & 1023, k = (tid>>10)&255, L = (tid>>18)&1, d = (tid>>19)&1;
  const float* src = (d ? rb : rf) + (size_t)L*262144 + (size_t)k*1024 + gcol;
  float sc = ((gcol>>8)==2) ? L2E2 : L2E;
  int g = gcol>>8, rem = gcol&255, slot = rem>>4, lo = rem&15;
  int ks = k>>5, hi = (k>>3)&3, j = k&7;
  int l = hi*16+lo, frag = ks*4+g;
  rp[(size_t)((d*2+L)*16 + slot)*16384 + (size_t)frag*512 + l*8 + j] = f2bf(*src * sc);
}

// ---- projection GEMM: xz[d][t*128+b][gc] = A @ W^T + bias*sc (all pre-scaled) ----
__global__ __launch_bounds__(256) void proj_gemm(
    const ushort_t* __restrict__ A_fw, const ushort_t* __restrict__ A_bw,
    const ushort_t* __restrict__ wt, int layer,
    const float* __restrict__ bias_fw, const float* __restrict__ bias_bw,
    ushort_t* __restrict__ xz)
{
  int d = blockIdx.z;
  const ushort_t* A = d ? A_bw : A_fw;
  const ushort_t* W = wt + (size_t)(d*2+layer)*262144;
  const float* bias = (d ? bias_bw : bias_fw) + layer*1024;
  ushort_t* out = xz + (size_t)d*TB*NG;
  int m0 = blockIdx.x*128, n0 = blockIdx.y*128;
  __shared__ ushort_t As[128*32];
  __shared__ ushort_t Bs[128*32];
  int tid = threadIdx.x;
  int w = tid>>6, l = tid&63, lo = l&15, hi = l>>4;
  int wm = w>>1, wn = w&1;
  v4f acc[4][4];
  #pragma unroll
  for (int i=0;i<4;++i)
    #pragma unroll
    for (int j=0;j<4;++j) acc[i][j] = (v4f){0.f,0.f,0.f,0.f};
  for (int kt=0; kt<8; ++kt){
    __syncthreads();
    #pragma unroll
    for (int p=0;p<2;++p){
      int c = tid + p*256;
      int row = c>>2, c4 = c&3;
      *(v4u*)(As + (size_t)c*8) = *(const v4u*)(A + (size_t)(m0+row)*256 + kt*32 + c4*8);
      *(v4u*)(Bs + (size_t)c*8) = *(const v4u*)(W + (size_t)(n0+row)*256 + kt*32 + c4*8);
    }
    __syncthreads();
    v8s af[4], bfv[4];
    #pragma unroll
    for (int mt=0;mt<4;++mt) af[mt] = *(const v8s*)(As + (size_t)(wm*64+mt*16+lo)*32 + hi*8);
    #pragma unroll
    for (int nt=0;nt<4;++nt) bfv[nt] = *(const v8s*)(Bs + (size_t)(wn*64+nt*16+lo)*32 + hi*8);
    #pragma unroll
    for (int mt=0;mt<4;++mt)
      #pragma unroll
      for (int nt=0;nt<4;++nt)
        acc[mt][nt] = __builtin_amdgcn_mfma_f32_16x16x32_bf16(af[mt], bfv[nt], acc[mt][nt], 0,0,0);
  }
  #pragma unroll
  for (int nt=0;nt<4;++nt){
    int col = n0 + wn*64 + nt*16 + lo;
    float bv = bias[col] * (((col>>8)==2) ? L2E2 : L2E);
    #pragma unroll
    for (int mt=0;mt<4;++mt){
      int row0 = m0 + wm*64 + mt*16 + hi*4;
      #pragma unroll
      for (int r=0;r<4;++r)
        out[(size_t)(row0+r)*NG + col] = f2bf(acc[mt][nt][r] + bv);
    }
  }
}

// ---- persistent LSTM recurrence ----
// 64 blocks x 256 thr (1 wave/SIMD -> full VGPR budget, R-frags stay in regs).
// g = bid&15 (group: d=g>>3, bg=g&7 -> 16 batch rows), cw = bid>>4.
// The 4 cw blocks of a group share bid%8 -> same XCD for L2-local flag/h exchange.
// Per-wave flag slots: flg[g][step][16]; signal = lane0 release-store; wait = 16-lane poll + __all.
// Spin is BOUNDED: a lost flag turns into a wrong answer, never a GPU hang.
__global__ __launch_bounds__(256,1) void rec_lstm(
    const ushort_t* __restrict__ xz, const ushort_t* __restrict__ rp,
    ushort_t* __restrict__ hbase, unsigned* __restrict__ flags, int layer)
{
  int bid = blockIdx.x;
  int g = bid & 15, cw = bid >> 4;
  int d = g >> 3, bg = g & 7;
  int rev = d;               // d==1 is the backward direction
  int tid = threadIdx.x, w = tid>>6, l = tid&63, lo = l&15, hi = l>>4;
  int b0 = bg*16;
  int U0 = cw*64 + w*16;
  int slot = cw*4 + w;
  const ushort_t* xzd = xz + (size_t)d*TB*NG;
  ushort_t* h = hbase + (size_t)d*TB*UU;
  unsigned* flg = flags + (size_t)g*4096;   // 256 steps x 16 slots

  v8s bfr[8][4];
  {
    const ushort_t* rpp = rp + (size_t)((d*2+layer)*16 + slot)*16384 + l*8;
    #pragma unroll
    for (int f=0;f<32;++f)
      ((v8s*)bfr)[f] = *(const v8s*)(rpp + (size_t)f*512);
  }
  float c[4] = {0.f,0.f,0.f,0.f};

  for (int s=0;s<256;++s){
    int t = rev ? 255-s : s;
    // xz prefetch (independent of h; issued before the spin)
    float xzv[4][4];
    #pragma unroll
    for (int gg=0;gg<4;++gg)
      #pragma unroll
      for (int r=0;r<4;++r)
        xzv[gg][r] = bf2f(xzd[(size_t)(t*128 + b0 + hi*4 + r)*NG + gg*256 + U0 + lo]);
    v4f acc[4];
    #pragma unroll
    for (int gg=0;gg<4;++gg) acc[gg] = (v4f){0.f,0.f,0.f,0.f};
    if (s>0){
      unsigned v; int spin = 0;
      do {
        v = __hip_atomic_load(&flg[(s-1)*16 + (l&15)], __ATOMIC_ACQUIRE, __HIP_MEMORY_SCOPE_AGENT);
        if (++spin > 200000) break;   // failsafe: wrong-answer beats GPU hang
      } while (!__all(v != 0u));
      int tp = rev ? t+1 : t-1;
      v8s a[8];
      #pragma unroll
      for (int ks=0;ks<8;++ks)
        a[ks] = *(const v8s*)(h + (size_t)(tp*128 + b0 + lo)*UU + ks*32 + hi*8);
      #pragma unroll
      for (int ks=0;ks<8;++ks)
        #pragma unroll
        for (int gg=0;gg<4;++gg)
          acc[gg] = __builtin_amdgcn_mfma_f32_16x16x32_bf16(a[ks], bfr[ks][gg], acc[gg], 0,0,0);
    }
    #pragma unroll
    for (int r=0;r<4;++r){
      float zi = acc[0][r] + xzv[0][r];   // pre-scaled by log2e
      float zf = acc[1][r] + xzv[1][r];
      float zg = acc[2][r] + xzv[2][r];   // pre-scaled by 2*log2e
      float zo = acc[3][r] + xzv[3][r];
      float ig = __builtin_amdgcn_rcpf(1.f + __builtin_amdgcn_exp2f(-zi));
      float fg = __builtin_amdgcn_rcpf(1.f + __builtin_amdgcn_exp2f(-zf));
      float og = __builtin_amdgcn_rcpf(1.f + __builtin_amdgcn_exp2f(-zo));
      float gt = 1.f - 2.f*__builtin_amdgcn_rcpf(1.f + __builtin_amdgcn_exp2f(zg));
      float cc = fg*c[r] + ig*gt;
      c[r] = cc;
      float th = 1.f - 2.f*__builtin_amdgcn_rcpf(1.f + __builtin_amdgcn_exp2f(L2E2*cc));
      h[(size_t)(t*128 + b0 + hi*4 + r)*UU + U0 + lo] = f2bf(og*th);
    }
    // per-wave release: vmcnt(0) drains this wave's h stores, then publish slot
    if (l == 0)
      __hip_atomic_store(&flg[s*16 + slot], 1u, __ATOMIC_RELEASE, __HIP_MEMORY_SCOPE_AGENT);
  }
}

// ---- final combine: out(B,T,U) fp32 = 0.5*(h1f + h0f + h1b + h0b) ----
__global__ void combine(const ushort_t* __restrict__ h, float* __restrict__ out){
  int tid = blockIdx.x*256 + threadIdx.x;
  int idx = tid*4;
  if (idx >= BB*TT*UU) return;
  int u = idx&255, t = (idx>>8)&255, b = idx>>16;
  size_t o = (size_t)(t*128+b)*256 + u;
  const size_t S = (size_t)TB*UU;
  v4h a0 = *(const v4h*)(h + 0*S + o);   // L0 fw
  v4h a1 = *(const v4h*)(h + 1*S + o);   // L0 bw
  v4h a2 = *(const v4h*)(h + 2*S + o);   // L1 fw
  v4h a3 = *(const v4h*)(h + 3*S + o);   // L1 bw
  v4f res;
  #pragma unroll
  for (int k=0;k<4;++k)
    res[k] = 0.5f*(bf2f(a0[k]) + bf2f(a1[k]) + bf2f(a2[k]) + bf2f(a3[k]));
  *(v4f*)(out + ((size_t)(b*256+t))*256 + u) = res;
}

extern "C" void kernel_launch(void* const* d_in, const int* in_sizes, int n_in,
                              void* d_out, int out_size, void* d_ws, size_t ws_size,
                              hipStream_t stream)
{
  const float* x  = (const float*)d_in[0];
  const float* wf = (const float*)d_in[1];
  const float* rf = (const float*)d_in[2];
  const float* bf = (const float*)d_in[3];
  const float* wb = (const float*)d_in[4];
  const float* rb = (const float*)d_in[5];
  const float* bb = (const float*)d_in[6];
  char* ws = (char*)d_ws;

  const size_t XB_OFF = 0;                                   // 16,777,216
  const size_t WT_OFF = XB_OFF + (size_t)TB*DD*2;
  const size_t RP_OFF = WT_OFF + (size_t)2*2*1024*256*2;     // +2,097,152
  const size_t XZ_OFF = RP_OFF + (size_t)2*2*256*1024*2;     // +2,097,152
  const size_t H_OFF  = XZ_OFF + (size_t)2*TB*NG*2;          // +134,217,728
  const size_t FL_OFF = H_OFF  + (size_t)4*TB*UU*2;          // +67,108,864

  ushort_t* xb = (ushort_t*)(ws + XB_OFF);
  ushort_t* wt = (ushort_t*)(ws + WT_OFF);
  ushort_t* rp = (ushort_t*)(ws + RP_OFF);
  ushort_t* xz = (ushort_t*)(ws + XZ_OFF);
  ushort_t* h  = (ushort_t*)(ws + H_OFF);
  unsigned* flags = (unsigned*)(ws + FL_OFF);
  const size_t S = (size_t)TB*UU;
  const size_t FL_PER_LAYER = 16*256*16;   // groups x steps x slots (uints)

  hipMemsetAsync(flags, 0, 2*FL_PER_LAYER*4, stream);
  prep_x<<<8192,256,0,stream>>>(x, xb);
  prep_w<<<4096,256,0,stream>>>(wf, wb, wt);
  prep_r<<<4096,256,0,stream>>>(rf, rb, rp);
  // layer 0
  proj_gemm<<<dim3(256,8,2),256,0,stream>>>(xb, xb, wt, 0, bf, bb, xz);
  rec_lstm<<<64,256,0,stream>>>(xz, rp, h, flags, 0);
  // layer 1 (input = layer-0 h series; residual handled in combine)
  proj_gemm<<<dim3(256,8,2),256,0,stream>>>(h, h + S, wt, 1, bf, bb, xz);
  rec_lstm<<<64,256,0,stream>>>(xz, rp, h + 2*S, flags + FL_PER_LAYER, 1);
  // merge: 0.5*((h1f+h0f)+(h1b+h0b))
  combine<<<8192,256,0,stream>>>(h, (float*)d_out);
}

// Round 10
// 1834.572 us; speedup vs baseline: 3.0008x; 3.0008x over previous
//
#include <hip/hip_runtime.h>

typedef unsigned short ushort_t;
typedef __attribute__((ext_vector_type(8))) short v8s;
typedef __attribute__((ext_vector_type(4))) float v4f;
typedef __attribute__((ext_vector_type(4))) unsigned int v4u;
typedef __attribute__((ext_vector_type(4))) unsigned short v4h;

#define DEV __device__ __forceinline__

#define BB 128
#define TT 256
#define DD 256
#define UU 256
#define NG 1024
#define TB 32768  // T*B

#define L2E  1.4426950408889634f
#define L2E2 2.8853901617779268f

DEV ushort_t f2bf(float f){
  unsigned u = __builtin_bit_cast(unsigned, f);
  u = u + 0x7FFFu + ((u>>16)&1u);
  return (ushort_t)(u>>16);
}
DEV float bf2f(ushort_t h){
  unsigned u = ((unsigned)h)<<16;
  return __builtin_bit_cast(float, u);
}
// write-through store (L3-visible, no cache maintenance)
DEV void store_short_wt(ushort_t* p, ushort_t v){
  asm volatile("global_store_short %0, %1, off sc0 sc1" :: "v"(p), "v"((unsigned)v) : "memory");
}

// ---- prep: x (B,T,D) fp32 -> xb (T,B,D) bf16 ----
__global__ void prep_x(const float* __restrict__ x, ushort_t* __restrict__ xb){
  int tid = blockIdx.x*256 + threadIdx.x;
  int idx = tid*4;
  if (idx >= BB*TT*DD) return;
  int d0 = idx & 255, t = (idx>>8)&255, b = idx>>16;
  const float* s = x + ((size_t)(b*256+t))*256 + d0;
  ushort_t* o = xb + ((size_t)(t*128+b))*256 + d0;
  v4f v = *(const v4f*)s;
  o[0]=f2bf(v[0]); o[1]=f2bf(v[1]); o[2]=f2bf(v[2]); o[3]=f2bf(v[3]);
}

// ---- prep: W (L,K=256,N=1024) fp32 -> wt [d][L][n][k] bf16, pre-scaled by log2e ----
__global__ void prep_w(const float* __restrict__ wf, const float* __restrict__ wb,
                       ushort_t* __restrict__ wt){
  int tid = blockIdx.x*256 + threadIdx.x;           // 1,048,576 total
  int n = tid & 1023, k = (tid>>10)&255, L = (tid>>18)&1, d = (tid>>19)&1;
  const float* src = (d ? wb : wf) + (size_t)L*262144 + (size_t)k*1024 + n;
  float sc = ((n>>8)==2) ? L2E2 : L2E;
  wt[(size_t)((d*2+L)*1024 + n)*256 + k] = f2bf(*src * sc);
}

// ---- prep: R (L,256,1024) fp32 -> rp packed in MFMA B-fragment order, pre-scaled ----
__global__ void prep_r(const float* __restrict__ rf, const float* __restrict__ rb,
                       ushort_t* __restrict__ rp){
  int tid = blockIdx.x*256 + threadIdx.x;           // 1,048,576 total
  int gcol = tid & 1023, k = (tid>>10)&255, L = (tid>>18)&1, d = (tid>>19)&1;
  const float* src = (d ? rb : rf) + (size_t)L*262144 + (size_t)k*1024 + gcol;
  float sc = ((gcol>>8)==2) ? L2E2 : L2E;
  int g = gcol>>8, rem = gcol&255, slot = rem>>4, lo = rem&15;
  int ks = k>>5, hi = (k>>3)&3, j = k&7;
  int l = hi*16+lo, frag = ks*4+g;
  rp[(size_t)((d*2+L)*16 + slot)*16384 + (size_t)frag*512 + l*8 + j] = f2bf(*src * sc);
}

// ---- projection GEMM: xz[d][t*128+b][gc] = A @ W^T + bias*sc (all pre-scaled) ----
__global__ __launch_bounds__(256) void proj_gemm(
    const ushort_t* __restrict__ A_fw, const ushort_t* __restrict__ A_bw,
    const ushort_t* __restrict__ wt, int layer,
    const float* __restrict__ bias_fw, const float* __restrict__ bias_bw,
    ushort_t* __restrict__ xz)
{
  int d = blockIdx.z;
  const ushort_t* A = d ? A_bw : A_fw;
  const ushort_t* W = wt + (size_t)(d*2+layer)*262144;
  const float* bias = (d ? bias_bw : bias_fw) + layer*1024;
  ushort_t* out = xz + (size_t)d*TB*NG;
  int m0 = blockIdx.x*128, n0 = blockIdx.y*128;
  __shared__ ushort_t As[128*32];
  __shared__ ushort_t Bs[128*32];
  int tid = threadIdx.x;
  int w = tid>>6, l = tid&63, lo = l&15, hi = l>>4;
  int wm = w>>1, wn = w&1;
  v4f acc[4][4];
  #pragma unroll
  for (int i=0;i<4;++i)
    #pragma unroll
    for (int j=0;j<4;++j) acc[i][j] = (v4f){0.f,0.f,0.f,0.f};
  for (int kt=0; kt<8; ++kt){
    __syncthreads();
    #pragma unroll
    for (int p=0;p<2;++p){
      int c = tid + p*256;
      int row = c>>2, c4 = c&3;
      *(v4u*)(As + (size_t)c*8) = *(const v4u*)(A + (size_t)(m0+row)*256 + kt*32 + c4*8);
      *(v4u*)(Bs + (size_t)c*8) = *(const v4u*)(W + (size_t)(n0+row)*256 + kt*32 + c4*8);
    }
    __syncthreads();
    v8s af[4], bfv[4];
    #pragma unroll
    for (int mt=0;mt<4;++mt) af[mt] = *(const v8s*)(As + (size_t)(wm*64+mt*16+lo)*32 + hi*8);
    #pragma unroll
    for (int nt=0;nt<4;++nt) bfv[nt] = *(const v8s*)(Bs + (size_t)(wn*64+nt*16+lo)*32 + hi*8);
    #pragma unroll
    for (int mt=0;mt<4;++mt)
      #pragma unroll
      for (int nt=0;nt<4;++nt)
        acc[mt][nt] = __builtin_amdgcn_mfma_f32_16x16x32_bf16(af[mt], bfv[nt], acc[mt][nt], 0,0,0);
  }
  #pragma unroll
  for (int nt=0;nt<4;++nt){
    int col = n0 + wn*64 + nt*16 + lo;
    float bv = bias[col] * (((col>>8)==2) ? L2E2 : L2E);
    #pragma unroll
    for (int mt=0;mt<4;++mt){
      int row0 = m0 + wm*64 + mt*16 + hi*4;
      #pragma unroll
      for (int r=0;r<4;++r)
        out[(size_t)(row0+r)*NG + col] = f2bf(acc[mt][nt][r] + bv);
    }
  }
}

// ---- persistent LSTM recurrence ----
// 64 blocks x 256 thr (1 wave/SIMD). g = bid&15 (d=g>>3, bg=g&7), cw = bid>>4.
// Sync protocol (NO cache maintenance anywhere):
//   producer: h stores write-through (sc0 sc1) -> s_waitcnt vmcnt(0) -> RELAXED flag store (sc1, L3)
//   consumer: RELAXED poll (sc1, L3) + __all, then plain h loads (first-touch lines, L3-fresh).
// Spin is BOUNDED: a lost flag turns into a wrong answer, never a GPU hang.
__global__ __launch_bounds__(256,1) void rec_lstm(
    const ushort_t* __restrict__ xz, const ushort_t* __restrict__ rp,
    ushort_t* __restrict__ hbase, unsigned* __restrict__ flags, int layer)
{
  int bid = blockIdx.x;
  int g = bid & 15, cw = bid >> 4;
  int d = g >> 3, bg = g & 7;
  int rev = d;               // d==1 is the backward direction
  int tid = threadIdx.x, w = tid>>6, l = tid&63, lo = l&15, hi = l>>4;
  int b0 = bg*16;
  int U0 = cw*64 + w*16;
  int slot = cw*4 + w;
  const ushort_t* xzd = xz + (size_t)d*TB*NG;
  ushort_t* h = hbase + (size_t)d*TB*UU;
  unsigned* flg = flags + (size_t)g*4096;   // 256 steps x 16 slots

  v8s bfr[8][4];
  {
    const ushort_t* rpp = rp + (size_t)((d*2+layer)*16 + slot)*16384 + l*8;
    #pragma unroll
    for (int f=0;f<32;++f)
      ((v8s*)bfr)[f] = *(const v8s*)(rpp + (size_t)f*512);
  }
  float c[4] = {0.f,0.f,0.f,0.f};

  for (int s=0;s<256;++s){
    int t = rev ? 255-s : s;
    // xz prefetch (independent of h; issued before the spin)
    float xzv[4][4];
    #pragma unroll
    for (int gg=0;gg<4;++gg)
      #pragma unroll
      for (int r=0;r<4;++r)
        xzv[gg][r] = bf2f(xzd[(size_t)(t*128 + b0 + hi*4 + r)*NG + gg*256 + U0 + lo]);
    v4f acc[4];
    #pragma unroll
    for (int gg=0;gg<4;++gg) acc[gg] = (v4f){0.f,0.f,0.f,0.f};
    if (s>0){
      unsigned v; int spin = 0;
      do {
        v = __hip_atomic_load(&flg[(s-1)*16 + (l&15)], __ATOMIC_RELAXED, __HIP_MEMORY_SCOPE_AGENT);
        if (++spin > 5000) break;   // failsafe: wrong-answer beats GPU hang
      } while (!__all(v != 0u));
      asm volatile("" ::: "memory");   // no hoisting h-loads above the poll
      int tp = rev ? t+1 : t-1;
      v8s a[8];
      #pragma unroll
      for (int ks=0;ks<8;++ks)
        a[ks] = *(const v8s*)(h + (size_t)(tp*128 + b0 + lo)*UU + ks*32 + hi*8);
      #pragma unroll
      for (int ks=0;ks<8;++ks)
        #pragma unroll
        for (int gg=0;gg<4;++gg)
          acc[gg] = __builtin_amdgcn_mfma_f32_16x16x32_bf16(a[ks], bfr[ks][gg], acc[gg], 0,0,0);
    }
    #pragma unroll
    for (int r=0;r<4;++r){
      float zi = acc[0][r] + xzv[0][r];   // pre-scaled by log2e
      float zf = acc[1][r] + xzv[1][r];
      float zg = acc[2][r] + xzv[2][r];   // pre-scaled by 2*log2e
      float zo = acc[3][r] + xzv[3][r];
      float ig = __builtin_amdgcn_rcpf(1.f + __builtin_amdgcn_exp2f(-zi));
      float fg = __builtin_amdgcn_rcpf(1.f + __builtin_amdgcn_exp2f(-zf));
      float og = __builtin_amdgcn_rcpf(1.f + __builtin_amdgcn_exp2f(-zo));
      float gt = 1.f - 2.f*__builtin_amdgcn_rcpf(1.f + __builtin_amdgcn_exp2f(zg));
      float cc = fg*c[r] + ig*gt;
      c[r] = cc;
      float th = 1.f - 2.f*__builtin_amdgcn_rcpf(1.f + __builtin_amdgcn_exp2f(L2E2*cc));
      store_short_wt(h + (size_t)(t*128 + b0 + hi*4 + r)*UU + U0 + lo, f2bf(og*th));
    }
    // drain write-through h stores to the coherence point, then publish (relaxed, sc1)
    asm volatile("s_waitcnt vmcnt(0)" ::: "memory");
    if (l == 0)
      __hip_atomic_store(&flg[s*16 + slot], 1u, __ATOMIC_RELAXED, __HIP_MEMORY_SCOPE_AGENT);
  }
}

// ---- final combine: out(B,T,U) fp32 = 0.5*(h1f + h0f + h1b + h0b) ----
__global__ void combine(const ushort_t* __restrict__ h, float* __restrict__ out){
  int tid = blockIdx.x*256 + threadIdx.x;
  int idx = tid*4;
  if (idx >= BB*TT*UU) return;
  int u = idx&255, t = (idx>>8)&255, b = idx>>16;
  size_t o = (size_t)(t*128+b)*256 + u;
  const size_t S = (size_t)TB*UU;
  v4h a0 = *(const v4h*)(h + 0*S + o);   // L0 fw
  v4h a1 = *(const v4h*)(h + 1*S + o);   // L0 bw
  v4h a2 = *(const v4h*)(h + 2*S + o);   // L1 fw
  v4h a3 = *(const v4h*)(h + 3*S + o);   // L1 bw
  v4f res;
  #pragma unroll
  for (int k=0;k<4;++k)
    res[k] = 0.5f*(bf2f(a0[k]) + bf2f(a1[k]) + bf2f(a2[k]) + bf2f(a3[k]));
  *(v4f*)(out + ((size_t)(b*256+t))*256 + u) = res;
}

extern "C" void kernel_launch(void* const* d_in, const int* in_sizes, int n_in,
                              void* d_out, int out_size, void* d_ws, size_t ws_size,
                              hipStream_t stream)
{
  const float* x  = (const float*)d_in[0];
  const float* wf = (const float*)d_in[1];
  const float* rf = (const float*)d_in[2];
  const float* bf = (const float*)d_in[3];
  const float* wb = (const float*)d_in[4];
  const float* rb = (const float*)d_in[5];
  const float* bb = (const float*)d_in[6];
  char* ws = (char*)d_ws;

  const size_t XB_OFF = 0;                                   // 16,777,216
  const size_t WT_OFF = XB_OFF + (size_t)TB*DD*2;
  const size_t RP_OFF = WT_OFF + (size_t)2*2*1024*256*2;     // +2,097,152
  const size_t XZ_OFF = RP_OFF + (size_t)2*2*256*1024*2;     // +2,097,152
  const size_t H_OFF  = XZ_OFF + (size_t)2*TB*NG*2;          // +134,217,728
  const size_t FL_OFF = H_OFF  + (size_t)4*TB*UU*2;          // +67,108,864

  ushort_t* xb = (ushort_t*)(ws + XB_OFF);
  ushort_t* wt = (ushort_t*)(ws + WT_OFF);
  ushort_t* rp = (ushort_t*)(ws + RP_OFF);
  ushort_t* xz = (ushort_t*)(ws + XZ_OFF);
  ushort_t* h  = (ushort_t*)(ws + H_OFF);
  unsigned* flags = (unsigned*)(ws + FL_OFF);
  const size_t S = (size_t)TB*UU;
  const size_t FL_PER_LAYER = 16*256*16;   // groups x steps x slots (uints)

  hipMemsetAsync(flags, 0, 2*FL_PER_LAYER*4, stream);
  prep_x<<<8192,256,0,stream>>>(x, xb);
  prep_w<<<4096,256,0,stream>>>(wf, wb, wt);
  prep_r<<<4096,256,0,stream>>>(rf, rb, rp);
  // layer 0
  proj_gemm<<<dim3(256,8,2),256,0,stream>>>(xb, xb, wt, 0, bf, bb, xz);
  rec_lstm<<<64,256,0,stream>>>(xz, rp, h, flags, 0);
  // layer 1 (input = layer-0 h series; residual handled in combine)
  proj_gemm<<<dim3(256,8,2),256,0,stream>>>(h, h + S, wt, 1, bf, bb, xz);
  rec_lstm<<<64,256,0,stream>>>(xz, rp, h + 2*S, flags + FL_PER_LAYER, 1);
  // merge: 0.5*((h1f+h0f)+(h1b+h0b))
  combine<<<8192,256,0,stream>>>(h, (float*)d_out);
}